// Round 1
// baseline (284.892 us; speedup 1.0000x reference)
//
#include <hip/hip_runtime.h>
#include <math.h>

#define DIMD 200
#define LL   256

static __device__ __forceinline__ float fexp2(float x) {
#if __has_builtin(__builtin_amdgcn_exp2f)
    return __builtin_amdgcn_exp2f(x);
#else
    return exp2f(x);
#endif
}
static __device__ __forceinline__ float frcp(float x) {
#if __has_builtin(__builtin_amdgcn_rcpf)
    return __builtin_amdgcn_rcpf(x);
#else
    return 1.0f / x;
#endif
}

// K1: embedding gather + mask bits + h = elu(xx@Wh+bh) + h1 = h@W1, h2b = h@W2 + b
// 8 rows per block, 256 blocks. Also writes channel-major transposed copies for K2.
__global__ __launch_bounds__(256) void k1_embed_h(
    const int* __restrict__ x, const float* __restrict__ emb,
    const float* __restrict__ Wh_w, const float* __restrict__ Wh_b,
    const float* __restrict__ W1_w, const float* __restrict__ W2_w,
    const float* __restrict__ bvec,
    unsigned* __restrict__ maskbits,
    float* __restrict__ h, float* __restrict__ hT,
    float* __restrict__ h1T, float* __restrict__ h2bT)
{
    __shared__ float xx[8][DIMD];
    __shared__ float hrow[8][DIMD];
    const int row0 = blockIdx.x * 8;
    const int b = row0 >> 8;       // 256 rows per batch, blocks never straddle batches
    const int l0 = row0 & 255;
    const int tid = threadIdx.x;

    for (int i = tid; i < 8 * DIMD; i += 256) {
        int r = i / DIMD;
        int e = i - r * DIMD;
        int tok = x[row0 + r];
        float v = emb[tok * DIMD + e];
        xx[r][e] = v;
        if (v == 1.0f) {  // faithful: float compare of embedding value vs PAD=1
            int l = l0 + r;
            atomicOr(&maskbits[(b * DIMD + e) * 8 + (l >> 5)], 1u << (l & 31));
        }
    }
    __syncthreads();

    const int e = tid;
    float hv[8];
    if (e < DIMD) {
        float acc[8];
        float bias = Wh_b[e];
#pragma unroll
        for (int r = 0; r < 8; r++) acc[r] = bias;
        for (int k = 0; k < DIMD; k++) {
            float w = Wh_w[k * DIMD + e];
#pragma unroll
            for (int r = 0; r < 8; r++) acc[r] = fmaf(xx[r][k], w, acc[r]);
        }
#pragma unroll
        for (int r = 0; r < 8; r++) {
            float a = acc[r];
            hv[r] = a > 0.0f ? a : expm1f(a);   // elu, alpha=1
            hrow[r][e] = hv[r];
            h[(row0 + r) * DIMD + e] = hv[r];
        }
        float4* pT = (float4*)&hT[(b * DIMD + e) * LL + l0];
        pT[0] = make_float4(hv[0], hv[1], hv[2], hv[3]);
        pT[1] = make_float4(hv[4], hv[5], hv[6], hv[7]);
    }
    __syncthreads();
    if (e < DIMD) {
        float a1[8], a2[8];
        float bb = bvec[e];
#pragma unroll
        for (int r = 0; r < 8; r++) { a1[r] = 0.0f; a2[r] = bb; }
        for (int k = 0; k < DIMD; k++) {
            float w1 = W1_w[k * DIMD + e];
            float w2 = W2_w[k * DIMD + e];
#pragma unroll
            for (int r = 0; r < 8; r++) {
                a1[r] = fmaf(hrow[r][k], w1, a1[r]);
                a2[r] = fmaf(hrow[r][k], w2, a2[r]);
            }
        }
        float4* p1 = (float4*)&h1T[(b * DIMD + e) * LL + l0];
        p1[0] = make_float4(a1[0], a1[1], a1[2], a1[3]);
        p1[1] = make_float4(a1[4], a1[5], a1[6], a1[7]);
        float4* p2 = (float4*)&h2bT[(b * DIMD + e) * LL + l0];
        p2[0] = make_float4(a2[0], a2[1], a2[2], a2[3]);
        p2[1] = make_float4(a2[4], a2[5], a2[6], a2[7]);
    }
}

// K2: per-channel masked attention. One block per (b,e) channel; thread t = target row l.
// Computes both forward (m>l kept) and backward (m<l kept) softmax-weighted sums.
__global__ __launch_bounds__(256) void k2_attn(
    const float* __restrict__ h1T, const float* __restrict__ h2bT,
    const float* __restrict__ hT, const unsigned* __restrict__ maskbits,
    const float* __restrict__ cptr,
    float* __restrict__ sfwT, float* __restrict__ sbwT)
{
    __shared__ float4 pk[LL];
    const int be = blockIdx.x;          // b*200 + e
    const int base = be * LL;
    const int t = threadIdx.x;
    const float cval = cptr[0];
    const float L2E = 1.4426950408889634f;
    const float S = 2.0f * L2E / cval;   // arg scale: exp2(S*(h1+h2b)) = e^{2z}
    const float C = 2.0f * cval * L2E;   // softmax: p = exp2(-C*r + maskbias)

    unsigned mw = maskbits[be * 8 + (t >> 5)];
    int selfmask = (mw >> (t & 31)) & 1;
    float A = h1T[base + t] * S;
    float Bm = h2bT[base + t] * S;
    float hcv = hT[base + t];
    pk[t] = make_float4(Bm, selfmask ? -1e30f : 0.0f, hcv, 0.0f);
    __syncthreads();

    float sumf = 0.0f, accf = 0.0f, sumb = 0.0f, accb = 0.0f, hsum = 0.0f;
#pragma unroll 4
    for (int m = 0; m < LL; m++) {
        float4 p = pk[m];
        float e2z = fexp2(A + p.x);                 // e^{2z}
        float r = frcp(e2z + 1.0f);                 // v = c - 2c*r; v-c = -2c*r
        float pf = fexp2(fmaf(r, -C, p.y));         // exp(v-c), masked -> 0
        float qf = (m > t) ? pf : 0.0f;
        float qb = (m < t) ? pf : 0.0f;
        sumf += qf; accf = fmaf(qf, p.z, accf);
        sumb += qb; accb = fmaf(qb, p.z, accb);
        hsum += p.z;
    }
    float uni = hsum * (1.0f / 256.0f);   // all-masked row -> softmax uniform over all m
    float sf = (selfmask || sumf == 0.0f) ? uni : accf / sumf;
    float sb = (selfmask || sumb == 0.0f) ? uni : accb / sumb;
    sfwT[base + t] = sf;
    sbwT[base + t] = sb;
}

// K3: fusion gate f = sigmoid(s@Wf1 + h@Wf2 + b), u = f*h + (1-f)*s, for fw and bw; writes uu [2048,400]
__global__ __launch_bounds__(256) void k3_gate(
    const float* __restrict__ h, const float* __restrict__ sfwT, const float* __restrict__ sbwT,
    const float* __restrict__ Wf1, const float* __restrict__ Wf2, const float* __restrict__ Wf2_b,
    float* __restrict__ uu)
{
    __shared__ float hl[DIMD][8];
    __shared__ float sf[DIMD][8];
    __shared__ float sb[DIMD][8];
    const int row0 = blockIdx.x * 8;
    const int b = row0 >> 8;
    const int l0 = row0 & 255;
    const int tid = threadIdx.x;

    for (int i = tid; i < 8 * DIMD; i += 256) {
        int r = i / DIMD;
        int e = i - r * DIMD;
        hl[e][r] = h[(row0 + r) * DIMD + e];
    }
    for (int i = tid; i < 8 * DIMD; i += 256) {
        int e = i >> 3, j = i & 7;
        sf[e][j] = sfwT[(b * DIMD + e) * LL + l0 + j];
        sb[e][j] = sbwT[(b * DIMD + e) * LL + l0 + j];
    }
    __syncthreads();

    const int e = tid;
    if (e < DIMD) {
        float g2[8], gf[8], gb[8];
        float bias = Wf2_b[e];
#pragma unroll
        for (int r = 0; r < 8; r++) { g2[r] = bias; gf[r] = 0.0f; gb[r] = 0.0f; }
        for (int k = 0; k < DIMD; k++) {
            float w1 = Wf1[k * DIMD + e];
            float w2 = Wf2[k * DIMD + e];
#pragma unroll
            for (int r = 0; r < 8; r++) {
                g2[r] = fmaf(hl[k][r], w2, g2[r]);
                gf[r] = fmaf(sf[k][r], w1, gf[r]);
                gb[r] = fmaf(sb[k][r], w1, gb[r]);
            }
        }
#pragma unroll
        for (int r = 0; r < 8; r++) {
            float hvv = hl[e][r], sfv = sf[e][r], sbv = sb[e][r];
            float ffw = 1.0f / (1.0f + expf(-(gf[r] + g2[r])));
            float fbw = 1.0f / (1.0f + expf(-(gb[r] + g2[r])));
            uu[(row0 + r) * 400 + e]       = ffw * hvv + (1.0f - ffw) * sfv;
            uu[(row0 + r) * 400 + 200 + e] = fbw * hvv + (1.0f - fbw) * sbv;
        }
    }
}

// K4: att_s = elu(uu@Ws1+b1)@Ws+b2; s_s[b,:] += sum_l uu*att_s  (atomic accumulate)
__global__ __launch_bounds__(512) void k4_pool(
    const float* __restrict__ uu, const float* __restrict__ Ws1_w, const float* __restrict__ Ws1_b,
    const float* __restrict__ Ws_w, const float* __restrict__ Ws_b,
    float* __restrict__ s_s)
{
    __shared__ float ul[400][8];
    __shared__ float t1[400][8];
    const int row0 = blockIdx.x * 8;
    const int b = row0 >> 8;
    const int tid = threadIdx.x;

    for (int i = tid; i < 8 * 400; i += 512) {
        int r = i / 400;
        int e = i - r * 400;
        ul[e][r] = uu[(row0 + r) * 400 + e];
    }
    __syncthreads();

    const int e = tid;
    if (e < 400) {
        float acc[8];
        float bias = Ws1_b[e];
#pragma unroll
        for (int r = 0; r < 8; r++) acc[r] = bias;
        for (int k = 0; k < 400; k++) {
            float w = Ws1_w[k * 400 + e];
#pragma unroll
            for (int r = 0; r < 8; r++) acc[r] = fmaf(ul[k][r], w, acc[r]);
        }
#pragma unroll
        for (int r = 0; r < 8; r++) {
            float a = acc[r];
            t1[e][r] = a > 0.0f ? a : expm1f(a);
        }
    }
    __syncthreads();
    if (e < 400) {
        float acc[8];
        float bias = Ws_b[e];
#pragma unroll
        for (int r = 0; r < 8; r++) acc[r] = bias;
        for (int k = 0; k < 400; k++) {
            float w = Ws_w[k * 400 + e];
#pragma unroll
            for (int r = 0; r < 8; r++) acc[r] = fmaf(t1[k][r], w, acc[r]);
        }
        float part = 0.0f;
#pragma unroll
        for (int r = 0; r < 8; r++) part = fmaf(ul[e][r], acc[r], part);
        atomicAdd(&s_s[b * 400 + e], part);
    }
}

// K5: y = relu(s_s@F1+b)@F2+b2; one block per batch element
__global__ __launch_bounds__(256) void k5_final(
    const float* __restrict__ s_s, const float* __restrict__ F1_w, const float* __restrict__ F1_b,
    const float* __restrict__ F2_w, const float* __restrict__ F2_b,
    float* __restrict__ y)
{
    const int b = blockIdx.x;
    const int e = threadIdx.x;
    __shared__ float red[256];
    float val = 0.0f;
    if (e < DIMD) {
        float a = F1_b[e];
        for (int k = 0; k < 400; k++) a = fmaf(s_s[b * 400 + k], F1_w[k * DIMD + e], a);
        a = a > 0.0f ? a : 0.0f;
        val = a * F2_w[e];
    }
    red[e] = val;
    __syncthreads();
    for (int s = 128; s > 0; s >>= 1) {
        if (e < s) red[e] += red[e + s];
        __syncthreads();
    }
    if (e == 0) y[b] = red[0] + F2_b[0];
}

extern "C" void kernel_launch(void* const* d_in, const int* in_sizes, int n_in,
                              void* d_out, int out_size, void* d_ws, size_t ws_size,
                              hipStream_t stream)
{
    const int*   x     = (const int*)  d_in[0];
    const float* emb   = (const float*)d_in[1];
    const float* Wh_w  = (const float*)d_in[2];
    const float* Wh_b  = (const float*)d_in[3];
    const float* W1_w  = (const float*)d_in[4];
    const float* W2_w  = (const float*)d_in[5];
    const float* bvec  = (const float*)d_in[6];
    const float* cptr  = (const float*)d_in[7];
    const float* Wf1_w = (const float*)d_in[8];
    const float* Wf2_w = (const float*)d_in[9];
    const float* Wf2_b = (const float*)d_in[10];
    const float* Ws1_w = (const float*)d_in[11];
    const float* Ws1_b = (const float*)d_in[12];
    const float* Ws_w  = (const float*)d_in[13];
    const float* Ws_b  = (const float*)d_in[14];
    const float* F1_w  = (const float*)d_in[15];
    const float* F1_b  = (const float*)d_in[16];
    const float* F2_w  = (const float*)d_in[17];
    const float* F2_b  = (const float*)d_in[18];
    float* out = (float*)d_out;

    char* ws = (char*)d_ws;
    unsigned* maskbits = (unsigned*)(ws + 0);            // 8*200*8 u32 = 51200 B
    float* s_s  = (float*)(ws + 51200);                  // 8*400 f32 = 12800 B
    const size_t M = 1638400;                            // 2048*200*4
    float* h    = (float*)(ws + 64000);
    float* hT   = (float*)(ws + 64000 + 1 * M);
    float* h1T  = (float*)(ws + 64000 + 2 * M);
    float* h2bT = (float*)(ws + 64000 + 3 * M);
    float* sfwT = (float*)(ws + 64000 + 4 * M);
    float* sbwT = (float*)(ws + 64000 + 5 * M);
    float* uu   = (float*)(ws + 64000 + 6 * M);          // 2048*400*4 = 3276800 B

    hipMemsetAsync(d_ws, 0, 64000, stream);              // zero maskbits + s_s

    hipLaunchKernelGGL(k1_embed_h, dim3(256), dim3(256), 0, stream,
                       x, emb, Wh_w, Wh_b, W1_w, W2_w, bvec, maskbits, h, hT, h1T, h2bT);
    hipLaunchKernelGGL(k2_attn, dim3(8 * DIMD), dim3(256), 0, stream,
                       h1T, h2bT, hT, maskbits, cptr, sfwT, sbwT);
    hipLaunchKernelGGL(k3_gate, dim3(256), dim3(256), 0, stream,
                       h, sfwT, sbwT, Wf1_w, Wf2_w, Wf2_b, uu);
    hipLaunchKernelGGL(k4_pool, dim3(256), dim3(512), 0, stream,
                       uu, Ws1_w, Ws1_b, Ws_w, Ws_b, s_s);
    hipLaunchKernelGGL(k5_final, dim3(8), dim3(256), 0, stream,
                       s_s, F1_w, F1_b, F2_w, F2_b, out);
}